// Round 9
// baseline (1208.049 us; speedup 1.0000x reference)
//
#include <hip/hip_runtime.h>
#include <hip/hip_bf16.h>
#include <stdint.h>

// ---------------------------------------------------------------------------
// E2E: LSTM1(8 steps) -> relu(linear)+BN1 -> concat -> xp2 -> LSTM2 tree(16)
//      -> BN2 -> out [1024,512] f32.
// R9: LSTM1 reverted to best-measured tile (MT=4, BN=128, BK=64, 32KB LDS)
// with R7 strength-reduced K-loop. Tree: per-level fused gather+GEMM+cell,
// gather ONCE into LDS before the K-loop (fixes R5's in-loop gather mistake),
// stream launches as the inter-level barrier (R7 device barriers = 1000us).
// ---------------------------------------------------------------------------

typedef __bf16 bf16;
typedef __bf16 bf16x8 __attribute__((ext_vector_type(8)));
typedef float f32x4 __attribute__((ext_vector_type(4)));

#define HIDDEN 512

__device__ __forceinline__ float fast_sig(float x) { return 1.f / (1.f + __expf(-x)); }
__device__ __forceinline__ float fast_tanh(float x) {
  float e = __expf(2.f * x);
  return 1.f - 2.f / (e + 1.f);
}

__device__ __forceinline__ void async16(const bf16* g, bf16* l) {
  __builtin_amdgcn_global_load_lds(
      (const __attribute__((address_space(1))) void*)g,
      (__attribute__((address_space(3))) void*)l, 16, 0, 0);
}

// ---------------- merged prep: cvts + detect ----------------
__device__ __forceinline__ void cvt_one(const float* __restrict__ src,
                                        bf16* __restrict__ dst, size_t i) {
  float4 a = *(const float4*)(src + i);
  float4 b = *(const float4*)(src + i + 4);
  bf16x8 r;
  r[0] = (bf16)a.x; r[1] = (bf16)a.y; r[2] = (bf16)a.z; r[3] = (bf16)a.w;
  r[4] = (bf16)b.x; r[5] = (bf16)b.y; r[6] = (bf16)b.z; r[7] = (bf16)b.w;
  *(bf16x8*)(dst + i) = r;
}

__global__ void prep(const float* conds, bf16* conds_b,
                     const float* s0, bf16* d0, const float* s1, bf16* d1,
                     const float* s2, bf16* d2, const float* s3, bf16* d3,
                     const float* s4, bf16* d4, const float* s5, bf16* d5,
                     const float* s6, bf16* d6,
                     const int* map, int* flags) {
  int b = blockIdx.x;
  int tid = threadIdx.x;
  if (b < 2176) {
    int g = b * 256 + tid;
    const float* s; bf16* d; int off;
    if      (g < 65536)  { s = s0; d = d0; off = g; }
    else if (g < 131072) { s = s1; d = d1; off = g - 65536; }
    else if (g < 196608) { s = s2; d = d2; off = g - 131072; }
    else if (g < 327680) { s = s3; d = d3; off = g - 196608; }
    else if (g < 344064) { s = s4; d = d4; off = g - 327680; }
    else if (g < 425984) { s = s5; d = d5; off = g - 344064; }
    else if (g < 557056) { s = s6; d = d6; off = g - 425984; }
    else return;
    cvt_one(s, d, (size_t)off * 8);
  } else if (b == 2176) {
    __shared__ int any;
    if (tid == 0) any = 0;
    __syncthreads();
    int loc = 0;
    for (int i = tid; i < 16384; i += 256) loc |= map[2 * i + 1];
    if (loc) atomicOr(&any, 1);
    __syncthreads();
    if (tid == 0) flags[0] = (any == 0) ? 1 : 0;
  } else {
    size_t i = ((size_t)(b - 2177) * 256 + tid) * 8;
    cvt_one(conds, conds_b, i);
  }
}

// ---------------- LSTM1 fused GEMM + cell (BM=128 x BN=128, BK=64) ---------
template <int MT, int KT0, int KT1>
__global__ __launch_bounds__(256, 2) void cell_gemm(
    const bf16* __restrict__ A0, int a0off, int a0s,
    const bf16* __restrict__ A1, int a1s,
    const bf16* __restrict__ B0, int b0s,
    const bf16* __restrict__ B1, int b1s,
    const float* __restrict__ bias0, const float* __restrict__ bias1,
    const float* __restrict__ c_prev,
    float* __restrict__ c_out,
    bf16* __restrict__ h_b16)
{
  constexpr int BM = MT * 32;
  __shared__ __align__(16) bf16 sA[BM * 64];
  __shared__ __align__(16) bf16 sB[128 * 64];
  const int tid = threadIdx.x;
  const int lane = tid & 63;
  const int quad = lane >> 4, cl = lane & 15;
  const int wave = tid >> 6;
  const int wr = wave >> 1, wc = wave & 1;
  const int bm0 = blockIdx.x * BM;
  const int j0 = blockIdx.y * 32;

  const bf16* ra[MT][2];
  const bf16* rb[4][2];
#pragma unroll
  for (int mi = 0; mi < MT; ++mi)
#pragma unroll
    for (int kh = 0; kh < 2; ++kh) {
      int row = wr * (MT * 16) + mi * 16 + cl;
      ra[mi][kh] = &sA[row * 64 + (((kh * 4 + quad) ^ (row & 7))) * 8];
    }
#pragma unroll
  for (int g = 0; g < 4; ++g)
#pragma unroll
    for (int kh = 0; kh < 2; ++kh) {
      int row = g * 32 + wc * 16 + cl;
      rb[g][kh] = &sB[row * 64 + (((kh * 4 + quad) ^ (row & 7))) * 8];
    }

  f32x4 acc[MT][4];
#pragma unroll
  for (int mi = 0; mi < MT; ++mi)
#pragma unroll
    for (int g = 0; g < 4; ++g) acc[mi][g] = f32x4{0.f, 0.f, 0.f, 0.f};

  const bf16* pa[MT];
  const bf16* pb[4];
#pragma unroll
  for (int ia = 0; ia < MT; ++ia) {
    int e = ia * 256 + tid, row = e >> 3, sl = e & 7;
    pa[ia] = A0 + (size_t)((bm0 + row) * a0s + a0off + (sl ^ (row & 7)) * 8);
  }
#pragma unroll
  for (int ib = 0; ib < 4; ++ib) {
    int e = ib * 256 + tid, row = e >> 3, sl = e & 7;
    int wrow = (row >> 5) * HIDDEN + j0 + (row & 31);
    pb[ib] = B0 + (size_t)(wrow * b0s + (sl ^ (row & 7)) * 8);
  }

  auto ktile = [&]() {
#pragma unroll
    for (int ia = 0; ia < MT; ++ia) {
      async16(pa[ia], sA + (ia * 256 + tid) * 8);
      pa[ia] += 64;
    }
#pragma unroll
    for (int ib = 0; ib < 4; ++ib) {
      async16(pb[ib], sB + (ib * 256 + tid) * 8);
      pb[ib] += 64;
    }
    __syncthreads();
#pragma unroll
    for (int kh = 0; kh < 2; ++kh) {
      bf16x8 af[MT], bfr[4];
#pragma unroll
      for (int mi = 0; mi < MT; ++mi) af[mi] = *(const bf16x8*)ra[mi][kh];
#pragma unroll
      for (int g = 0; g < 4; ++g) bfr[g] = *(const bf16x8*)rb[g][kh];
#pragma unroll
      for (int mi = 0; mi < MT; ++mi)
#pragma unroll
        for (int g = 0; g < 4; ++g)
          acc[mi][g] = __builtin_amdgcn_mfma_f32_16x16x32_bf16(af[mi], bfr[g], acc[mi][g], 0, 0, 0);
    }
    __syncthreads();
  };

  for (int kt = 0; kt < KT0; ++kt) ktile();
  if (KT1 > 0) {
#pragma unroll
    for (int ia = 0; ia < MT; ++ia) {
      int e = ia * 256 + tid, row = e >> 3, sl = e & 7;
      pa[ia] = A1 + (size_t)((bm0 + row) * a1s + (sl ^ (row & 7)) * 8);
    }
#pragma unroll
    for (int ib = 0; ib < 4; ++ib) {
      int e = ib * 256 + tid, row = e >> 3, sl = e & 7;
      int wrow = (row >> 5) * HIDDEN + j0 + (row & 31);
      pb[ib] = B1 + (size_t)(wrow * b1s + (sl ^ (row & 7)) * 8);
    }
    for (int kt = 0; kt < KT1; ++kt) ktile();
  }

  const int j = j0 + wc * 16 + cl;
  float bI = bias0[j] + bias1[j];
  float bF = bias0[HIDDEN + j] + bias1[HIDDEN + j];
  float bG = bias0[2 * HIDDEN + j] + bias1[2 * HIDDEN + j];
  float bO = bias0[3 * HIDDEN + j] + bias1[3 * HIDDEN + j];
#pragma unroll
  for (int mi = 0; mi < MT; ++mi) {
    int rb_ = bm0 + wr * (MT * 16) + mi * 16 + quad * 4;
#pragma unroll
    for (int r = 0; r < 4; ++r) {
      int row = rb_ + r;
      float iv = fast_sig(acc[mi][0][r] + bI);
      float fv = fast_sig(acc[mi][1][r] + bF);
      float gv = fast_tanh(acc[mi][2][r] + bG);
      float ov = fast_sig(acc[mi][3][r] + bO);
      float cp = c_prev ? c_prev[(size_t)row * HIDDEN + j] : 0.f;
      float cn = fv * cp + iv * gv;
      float hn = ov * fast_tanh(cn);
      c_out[(size_t)row * HIDDEN + j] = cn;
      h_b16[(size_t)row * HIDDEN + j] = (bf16)hn;
    }
  }
}

// ------- tree level, fused: LDS gather (up-front) + GEMM + cell ------------
// grid (32,16): BM=32 rows, 32 j x 4 gates. sA = full 32x512 gathered A.
__global__ __launch_bounds__(256, 2) void tree_fused(
    const int* __restrict__ map, const int* __restrict__ flags, int level,
    const bf16* __restrict__ h_src, const float* __restrict__ c_src,
    const bf16* __restrict__ W, const float* __restrict__ bhh,
    const void* __restrict__ xp, int xpf,
    bf16* __restrict__ h_dst, float* __restrict__ c_dst,
    float* __restrict__ hf)
{
  __shared__ __align__(16) bf16 sA[32 * 512];
  __shared__ __align__(16) bf16 sB[128 * 64];
  __shared__ int smap[64];
  const int tid = threadIdx.x;
  const int lane = tid & 63, wave = tid >> 6;
  const int quad = lane >> 4, cl = lane & 15;
  const int wr = wave >> 1, wc = wave & 1;
  const int bm0 = blockIdx.x * 32;
  const int j0 = blockIdx.y * 32;

  if (tid < 64) {
    long base = (long)level * 2048 + (bm0 + (tid >> 1)) * 2 + (tid & 1);
    smap[tid] = flags[0] ? map[base * 2] : map[base];
  }
  __syncthreads();

  // gather A = bf16(0.5*(h[m0-1]+h[m1-1])) into LDS, 16B-slot swizzled
  for (int u = tid; u < 2048; u += 256) {
    int row = u >> 6, slot = u & 63;
    int m0 = smap[row * 2], m1 = smap[row * 2 + 1];
    int col = slot * 8;
    float a8[8] = {0.f, 0.f, 0.f, 0.f, 0.f, 0.f, 0.f, 0.f};
    if (m0) {
      bf16x8 x = *(const bf16x8*)&h_src[(size_t)(m0 - 1) * HIDDEN + col];
#pragma unroll
      for (int q = 0; q < 8; ++q) a8[q] += (float)x[q];
    }
    if (m1) {
      bf16x8 x = *(const bf16x8*)&h_src[(size_t)(m1 - 1) * HIDDEN + col];
#pragma unroll
      for (int q = 0; q < 8; ++q) a8[q] += (float)x[q];
    }
    bf16x8 rr;
#pragma unroll
    for (int q = 0; q < 8; ++q) rr[q] = (bf16)(0.5f * a8[q]);
    *(bf16x8*)&sA[(row << 9) + ((slot ^ (row & 7)) << 3)] = rr;
  }

  const bf16* pb[4];
#pragma unroll
  for (int ib = 0; ib < 4; ++ib) {
    int e = ib * 256 + tid, row = e >> 3, sl = e & 7;
    int wrow = (row >> 5) * HIDDEN + j0 + (row & 31);
    pb[ib] = W + (size_t)(wrow * HIDDEN + (sl ^ (row & 7)) * 8);
  }

  f32x4 acc[4];
#pragma unroll
  for (int g = 0; g < 4; ++g) acc[g] = f32x4{0.f, 0.f, 0.f, 0.f};

  const int arow = wr * 16 + cl;
  for (int kt = 0; kt < 8; ++kt) {
#pragma unroll
    for (int ib = 0; ib < 4; ++ib) {
      async16(pb[ib], sB + (ib * 256 + tid) * 8);
      pb[ib] += 64;
    }
    __syncthreads();   // drains gather ds_writes (kt=0) + async B
#pragma unroll
    for (int kh = 0; kh < 2; ++kh) {
      int s = kt * 8 + kh * 4 + quad;
      bf16x8 af = *(const bf16x8*)&sA[(arow << 9) + ((s ^ (arow & 7)) << 3)];
#pragma unroll
      for (int g = 0; g < 4; ++g) {
        int brow = g * 32 + wc * 16 + cl;
        bf16x8 bfr = *(const bf16x8*)&sB[brow * 64 + (((kh * 4 + quad) ^ (brow & 7))) * 8];
        acc[g] = __builtin_amdgcn_mfma_f32_16x16x32_bf16(af, bfr, acc[g], 0, 0, 0);
      }
    }
    __syncthreads();
  }

  const int j = j0 + wc * 16 + cl;
  float bI = bhh[j], bF = bhh[HIDDEN + j];
  float bG = bhh[2 * HIDDEN + j], bO = bhh[3 * HIDDEN + j];
  int lr0 = wr * 16 + quad * 4;
#pragma unroll
  for (int r = 0; r < 4; ++r) {
    int lr = lr0 + r;
    int row = bm0 + lr;
    float gi = acc[0][r] + bI;
    float gf = acc[1][r] + bF;
    float gg = acc[2][r] + bG;
    float go = acc[3][r] + bO;
    size_t base = (size_t)row * 2048;
    if (xpf) {
      const float* xr = (const float*)xp + base;
      gi += xr[j]; gf += xr[HIDDEN + j];
      gg += xr[2 * HIDDEN + j]; go += xr[3 * HIDDEN + j];
    } else {
      const bf16* xr = (const bf16*)xp + base;
      gi += (float)xr[j]; gf += (float)xr[HIDDEN + j];
      gg += (float)xr[2 * HIDDEN + j]; go += (float)xr[3 * HIDDEN + j];
    }
    int m0 = smap[lr * 2], m1 = smap[lr * 2 + 1];
    float cp = 0.f;
    if (m0) cp += c_src[(size_t)(m0 - 1) * HIDDEN + j];
    if (m1) cp += c_src[(size_t)(m1 - 1) * HIDDEN + j];
    cp *= 0.5f;
    float cn = fast_sig(gf) * cp + fast_sig(gi) * fast_tanh(gg);
    float hn = fast_sig(go) * fast_tanh(cn);
    c_dst[(size_t)row * HIDDEN + j] = cn;
    h_dst[(size_t)row * HIDDEN + j] = (bf16)hn;
    if (hf) hf[(size_t)row * HIDDEN + j] = hn;
  }
}

// ---------------- plain GEMM (BK=32, swizzled): concat(A0,A1,A2)·B^T -------
template <int MT>
__global__ __launch_bounds__(256, 2) void plain_gemm(
    const bf16* __restrict__ A0, int a0s, int a0kt,
    const bf16* __restrict__ A1, int a1s, int a1kt,
    const bf16* __restrict__ A2, int a2s, int a2kt,
    const bf16* __restrict__ B, int bs,
    const float* __restrict__ bias, int do_relu,
    bf16* __restrict__ outh, float* __restrict__ outf, int Ntot)
{
  constexpr int BM = MT * 32;
  __shared__ __align__(16) bf16 sA[BM * 32];
  __shared__ __align__(16) bf16 sB[128 * 32];
  const int tid = threadIdx.x;
  const int lane = tid & 63;
  const int quad = lane >> 4, cl = lane & 15;
  const int wave = tid >> 6;
  const int wr = wave >> 1, wc = wave & 1;
  const int bm0 = blockIdx.x * BM;
  const int bn0 = blockIdx.y * 128;

  f32x4 acc[MT][4];
#pragma unroll
  for (int mi = 0; mi < MT; ++mi)
#pragma unroll
    for (int ni = 0; ni < 4; ++ni) acc[mi][ni] = f32x4{0.f, 0.f, 0.f, 0.f};

  const int nkt = a0kt + a1kt + a2kt;
  for (int kt = 0; kt < nkt; ++kt) {
    const bf16* abase; int astr, acol;
    if (kt < a0kt)            { abase = A0; astr = a0s; acol = kt * 32; }
    else if (kt < a0kt + a1kt){ abase = A1; astr = a1s; acol = (kt - a0kt) * 32; }
    else                      { abase = A2; astr = a2s; acol = (kt - a0kt - a1kt) * 32; }
#pragma unroll
    for (int ia = 0; ia < MT / 2; ++ia) {
      int e = ia * 256 + tid;
      int row = e >> 2, sl = e & 3;
      int src = sl ^ ((row >> 1) & 3);
      async16(abase + (size_t)(bm0 + row) * astr + acol + src * 8, sA + e * 8);
    }
#pragma unroll
    for (int ib = 0; ib < 2; ++ib) {
      int e = ib * 256 + tid;
      int row = e >> 2, sl = e & 3;
      int src = sl ^ ((row >> 1) & 3);
      async16(B + (size_t)(bn0 + row) * bs + kt * 32 + src * 8, sB + e * 8);
    }
    __syncthreads();
    bf16x8 af[MT], bfr[4];
#pragma unroll
    for (int mi = 0; mi < MT; ++mi) {
      int row = wr * (MT * 16) + mi * 16 + cl;
      int sl = quad ^ ((row >> 1) & 3);
      af[mi] = *(const bf16x8*)&sA[row * 32 + sl * 8];
    }
#pragma unroll
    for (int ni = 0; ni < 4; ++ni) {
      int row = wc * 64 + ni * 16 + cl;
      int sl = quad ^ ((row >> 1) & 3);
      bfr[ni] = *(const bf16x8*)&sB[row * 32 + sl * 8];
    }
#pragma unroll
    for (int mi = 0; mi < MT; ++mi)
#pragma unroll
      for (int ni = 0; ni < 4; ++ni)
        acc[mi][ni] = __builtin_amdgcn_mfma_f32_16x16x32_bf16(af[mi], bfr[ni], acc[mi][ni], 0, 0, 0);
    __syncthreads();
  }

#pragma unroll
  for (int mi = 0; mi < MT; ++mi) {
    int rb = bm0 + wr * (MT * 16) + mi * 16 + quad * 4;
#pragma unroll
    for (int ni = 0; ni < 4; ++ni) {
      int col = bn0 + wc * 64 + ni * 16 + cl;
      float bv = bias ? bias[col] : 0.f;
#pragma unroll
      for (int r = 0; r < 4; ++r) {
        int row = rb + r;
        float v = acc[mi][ni][r] + bv;
        if (do_relu) v = fmaxf(v, 0.f);
        if (outf) outf[(size_t)row * Ntot + col] = v;
        else      outh[(size_t)row * Ntot + col] = (bf16)v;
      }
    }
  }
}

// level-15 cell: zero state -> gates = xp2[15] + bhh
__global__ void cell0(const void* __restrict__ xp, int xp_f32,
                      const float* __restrict__ bhh,
                      bf16* __restrict__ h, float* __restrict__ c)
{
  int n = blockIdx.x, j = threadIdx.x;
  float g[4];
#pragma unroll
  for (int k = 0; k < 4; ++k) {
    size_t idx = (size_t)n * 2048 + k * 512 + j;
    float v = xp_f32 ? ((const float*)xp)[idx] : (float)((const bf16*)xp)[idx];
    g[k] = v + bhh[k * 512 + j];
  }
  float cv = fast_sig(g[0]) * fast_tanh(g[2]);
  h[(size_t)n * HIDDEN + j] = (bf16)(fast_sig(g[3]) * fast_tanh(cv));
  c[(size_t)n * HIDDEN + j] = cv;
}

// ---------------- deterministic batchnorm ----------------
__global__ void bn_reduce_b16(const bf16* __restrict__ x, int rpb, int F,
                              float* __restrict__ partials) {
  int col = threadIdx.x, b = blockIdx.x;
  const bf16* p = x + (size_t)b * rpb * F + col;
  float s = 0.f, q = 0.f;
  for (int r = 0; r < rpb; ++r) { float v = (float)p[(size_t)r * F]; s += v; q += v * v; }
  partials[(size_t)b * 2 * F + col] = s;
  partials[(size_t)b * 2 * F + F + col] = q;
}

__global__ void bn_reduce_f32(const float* __restrict__ x, int rpb, int F,
                              float* __restrict__ partials) {
  int col = threadIdx.x, b = blockIdx.x;
  const float* p = x + (size_t)b * rpb * F + col;
  float s = 0.f, q = 0.f;
  for (int r = 0; r < rpb; ++r) { float v = p[(size_t)r * F]; s += v; q += v * v; }
  partials[(size_t)b * 2 * F + col] = s;
  partials[(size_t)b * 2 * F + F + col] = q;
}

__global__ void bn_final(const float* __restrict__ partials, int nb, int F,
                         const float* __restrict__ g, const float* __restrict__ b,
                         float invB, float* __restrict__ scale, float* __restrict__ shift) {
  int j = threadIdx.x;
  float s = 0.f, q = 0.f;
  for (int i = 0; i < nb; ++i) {
    s += partials[(size_t)i * 2 * F + j];
    q += partials[(size_t)i * 2 * F + F + j];
  }
  float mu = s * invB;
  float var = fmaxf(q * invB - mu * mu, 0.f);
  float sc = g[j] * rsqrtf(var + 1e-5f);
  scale[j] = sc;
  shift[j] = b[j] - sc * mu;
}

__global__ void bn_apply_mid(const bf16* __restrict__ x, const float* __restrict__ scale,
                             const float* __restrict__ shift, int Fmask, size_t total,
                             bf16* __restrict__ out) {
  for (size_t i = blockIdx.x * (size_t)blockDim.x + threadIdx.x; i < total;
       i += (size_t)gridDim.x * blockDim.x) {
    int j = (int)(i & (size_t)Fmask);
    out[i] = (bf16)(scale[j] * (float)x[i] + shift[j]);
  }
}

__global__ void bn_apply_out(const float* __restrict__ x, const float* __restrict__ scale,
                             const float* __restrict__ shift, int Fmask, size_t total,
                             float* __restrict__ out) {
  for (size_t i = blockIdx.x * (size_t)blockDim.x + threadIdx.x; i < total;
       i += (size_t)gridDim.x * blockDim.x) {
    int j = (int)(i & (size_t)Fmask);
    out[i] = scale[j] * x[i] + shift[j];
  }
}

// ---------------------------------------------------------------------------
extern "C" void kernel_launch(void* const* d_in, const int* in_sizes, int n_in,
                              void* d_out, int out_size, void* d_ws, size_t ws_size,
                              hipStream_t stream) {
  const float* operators = (const float*)d_in[0];
  const float* extras    = (const float*)d_in[1];
  const float* conds     = (const float*)d_in[2];
  const int*   mapping   = (const int*)d_in[4];
  const float* b1ih = (const float*)d_in[7];
  const float* b1hh = (const float*)d_in[8];
  const float* condb = (const float*)d_in[10];
  const float* bn1g = (const float*)d_in[11];
  const float* bn1b = (const float*)d_in[12];
  const float* b2ih = (const float*)d_in[15];
  const float* b2hh = (const float*)d_in[16];
  const float* bn2g = (const float*)d_in[17];
  const float* bn2b = (const float*)d_in[18];

  char* ws = (char*)d_ws;
  size_t o = 0;
  auto alloc = [&](size_t bytes) {
    char* p = ws + o;
    o += (bytes + 255) & ~(size_t)255;
    return p;
  };
  bf16* conds_b = (bf16*)alloc((size_t)33554432 * 2);
  bf16* ops_b   = (bf16*)alloc((size_t)524288 * 2);
  bf16* ext_b   = (bf16*)alloc((size_t)524288 * 2);
  bf16* w1ih_b  = (bf16*)alloc((size_t)524288 * 2);
  bf16* w1hh_b  = (bf16*)alloc((size_t)1048576 * 2);
  bf16* condw_b = (bf16*)alloc((size_t)131072 * 2);
  bf16* w2ih_b  = (bf16*)alloc((size_t)655360 * 2);
  bf16* w2hh_b  = (bf16*)alloc((size_t)1048576 * 2);
  bf16* h1[2];
  h1[0] = (bf16*)alloc((size_t)16384 * 512 * 2);
  h1[1] = (bf16*)alloc((size_t)16384 * 512 * 2);
  float* c1 = (float*)alloc((size_t)16384 * 512 * 4);
  bf16* last_relu = (bf16*)alloc((size_t)16384 * 256 * 2);
  bf16* last_bn = (bf16*)alloc((size_t)16384 * 256 * 2);
  bf16* h2a = (bf16*)alloc((size_t)1024 * 512 * 2);
  bf16* h2b = (bf16*)alloc((size_t)1024 * 512 * 2);
  float* c2a = (float*)alloc((size_t)1024 * 512 * 4);
  float* c2b = (float*)alloc((size_t)1024 * 512 * 4);
  float* h2f = (float*)alloc((size_t)1024 * 512 * 4);
  float* partials = (float*)alloc((size_t)64 * 1024 * 4);
  float* scale1 = (float*)alloc(256 * 4);
  float* shift1 = (float*)alloc(256 * 4);
  float* scale2 = (float*)alloc(512 * 4);
  float* shift2 = (float*)alloc(512 * 4);
  int* flags = (int*)alloc(256);

  size_t xp2_elems = (size_t)16384 * 2048;
  int xpf = (o + xp2_elems * 4 <= ws_size) ? 1 : 0;
  void* xp2 = alloc(xp2_elems * (xpf ? 4 : 2));
  float* xp2f = xpf ? (float*)xp2 : nullptr;
  bf16* xp2h = xpf ? nullptr : (bf16*)xp2;

  prep<<<18561, 256, 0, stream>>>(
      conds, conds_b,
      operators, ops_b, extras, ext_b,
      (const float*)d_in[5], w1ih_b, (const float*)d_in[6], w1hh_b,
      (const float*)d_in[9], condw_b, (const float*)d_in[13], w2ih_b,
      (const float*)d_in[14], w2hh_b,
      mapping, flags);

  // -------- LSTM1: 8 fused K=768 GEMM+cell steps (BM=128 x BN=128) --------
  cell_gemm<4, 4, 0><<<dim3(128, 16), 256, 0, stream>>>(
      conds_b, 0, 2048, nullptr, 512,
      w1ih_b, 256, w1hh_b, 512,
      b1ih, b1hh, nullptr, c1, h1[1]);
  for (int t = 1; t < 8; ++t) {
    cell_gemm<4, 4, 8><<<dim3(128, 16), 256, 0, stream>>>(
        conds_b, t * 256, 2048, h1[t & 1], 512,
        w1ih_b, 256, w1hh_b, 512,
        b1ih, b1hh, c1, c1, h1[(t + 1) & 1]);
  }

  // -------- last = relu(h1 @ condW^T + condb); BN1 --------
  plain_gemm<2><<<dim3(256, 2), 256, 0, stream>>>(
      h1[0], 512, 16, nullptr, 0, 0, nullptr, 0, 0,
      condw_b, 512, condb, 1, last_relu, nullptr, 256);
  bn_reduce_b16<<<64, 256, 0, stream>>>(last_relu, 256, 256, partials);
  bn_final<<<1, 256, 0, stream>>>(partials, 64, 256, bn1g, bn1b, 1.f / 16384.f, scale1, shift1);
  bn_apply_mid<<<1024, 256, 0, stream>>>(last_relu, scale1, shift1, 255,
                                         (size_t)16384 * 256, last_bn);

  // -------- xp2 = concat(ops, extras, last_bn) @ W2ih^T + b2ih --------
  plain_gemm<4><<<dim3(128, 16), 256, 0, stream>>>(
      ops_b, 32, 1, ext_b, 32, 1, last_bn, 256, 8,
      w2ih_b, 320, b2ih, 0, xp2h, xp2f, 2048);

  // -------- LSTM2 tree: fused gather+GEMM+cell per level --------
  size_t lvl_sz = (size_t)1024 * 2048;
  const void* xp15 = xpf ? (const void*)(xp2f + 15 * lvl_sz) : (const void*)(xp2h + 15 * lvl_sz);
  cell0<<<1024, 512, 0, stream>>>(xp15, xpf, b2hh, h2a, c2a);
  int cur = 0;
  bf16* hbuf[2] = {h2a, h2b};
  float* cbuf[2] = {c2a, c2b};
  for (int idx = 14; idx >= 0; --idx) {
    const void* xpl = xpf ? (const void*)(xp2f + idx * lvl_sz) : (const void*)(xp2h + idx * lvl_sz);
    tree_fused<<<dim3(32, 16), 256, 0, stream>>>(
        mapping, flags, idx,
        hbuf[cur], cbuf[cur],
        w2hh_b, b2hh, xpl, xpf,
        hbuf[cur ^ 1], cbuf[cur ^ 1],
        (idx == 0) ? h2f : nullptr);
    cur ^= 1;
  }

  // -------- BN2 -> output --------
  bn_reduce_f32<<<16, 512, 0, stream>>>(h2f, 64, 512, partials);
  bn_final<<<1, 512, 0, stream>>>(partials, 16, 512, bn2g, bn2b, 1.f / 1024.f, scale2, shift2);
  bn_apply_out<<<512, 256, 0, stream>>>(h2f, scale2, shift2, 511,
                                        (size_t)1024 * 512, (float*)d_out);
}

// Round 10
// 1132.855 us; speedup vs baseline: 1.0664x; 1.0664x over previous
//
#include <hip/hip_runtime.h>
#include <hip/hip_bf16.h>
#include <stdint.h>

// ---------------------------------------------------------------------------
// E2E: LSTM1(8 steps) -> relu(linear)+BN1 -> concat -> xp2 -> LSTM2 tree(16)
//      -> BN2 -> out [1024,512] f32.
// R10: best-of-all-rounds assembly. LSTM1 = R9 strength-reduced (MT=4,BK=64).
// Tree = R8 split gather(1024 blk) + cell_tree GEMM (512 blk), both R9-style
// pointer-increment loops. xp2 stored bf16 (halves its write + tree reads;
// absmax history shows +0.001 only).
// ---------------------------------------------------------------------------

typedef __bf16 bf16;
typedef __bf16 bf16x8 __attribute__((ext_vector_type(8)));
typedef float f32x4 __attribute__((ext_vector_type(4)));

#define HIDDEN 512

__device__ __forceinline__ float fast_sig(float x) { return 1.f / (1.f + __expf(-x)); }
__device__ __forceinline__ float fast_tanh(float x) {
  float e = __expf(2.f * x);
  return 1.f - 2.f / (e + 1.f);
}

__device__ __forceinline__ void async16(const bf16* g, bf16* l) {
  __builtin_amdgcn_global_load_lds(
      (const __attribute__((address_space(1))) void*)g,
      (__attribute__((address_space(3))) void*)l, 16, 0, 0);
}

// ---------------- merged prep: cvts + detect ----------------
__device__ __forceinline__ void cvt_one(const float* __restrict__ src,
                                        bf16* __restrict__ dst, size_t i) {
  float4 a = *(const float4*)(src + i);
  float4 b = *(const float4*)(src + i + 4);
  bf16x8 r;
  r[0] = (bf16)a.x; r[1] = (bf16)a.y; r[2] = (bf16)a.z; r[3] = (bf16)a.w;
  r[4] = (bf16)b.x; r[5] = (bf16)b.y; r[6] = (bf16)b.z; r[7] = (bf16)b.w;
  *(bf16x8*)(dst + i) = r;
}

__global__ void prep(const float* conds, bf16* conds_b,
                     const float* s0, bf16* d0, const float* s1, bf16* d1,
                     const float* s2, bf16* d2, const float* s3, bf16* d3,
                     const float* s4, bf16* d4, const float* s5, bf16* d5,
                     const float* s6, bf16* d6,
                     const int* map, int* flags) {
  int b = blockIdx.x;
  int tid = threadIdx.x;
  if (b < 2176) {
    int g = b * 256 + tid;
    const float* s; bf16* d; int off;
    if      (g < 65536)  { s = s0; d = d0; off = g; }
    else if (g < 131072) { s = s1; d = d1; off = g - 65536; }
    else if (g < 196608) { s = s2; d = d2; off = g - 131072; }
    else if (g < 327680) { s = s3; d = d3; off = g - 196608; }
    else if (g < 344064) { s = s4; d = d4; off = g - 327680; }
    else if (g < 425984) { s = s5; d = d5; off = g - 344064; }
    else if (g < 557056) { s = s6; d = d6; off = g - 425984; }
    else return;
    cvt_one(s, d, (size_t)off * 8);
  } else if (b == 2176) {
    __shared__ int any;
    if (tid == 0) any = 0;
    __syncthreads();
    int loc = 0;
    for (int i = tid; i < 16384; i += 256) loc |= map[2 * i + 1];
    if (loc) atomicOr(&any, 1);
    __syncthreads();
    if (tid == 0) flags[0] = (any == 0) ? 1 : 0;
  } else {
    size_t i = ((size_t)(b - 2177) * 256 + tid) * 8;
    cvt_one(conds, conds_b, i);
  }
}

// ---------------- LSTM1 fused GEMM + cell (BM=128 x BN=128, BK=64) ---------
template <int MT, int KT0, int KT1>
__global__ __launch_bounds__(256, 2) void cell_gemm(
    const bf16* __restrict__ A0, int a0off, int a0s,
    const bf16* __restrict__ A1, int a1s,
    const bf16* __restrict__ B0, int b0s,
    const bf16* __restrict__ B1, int b1s,
    const float* __restrict__ bias0, const float* __restrict__ bias1,
    const float* __restrict__ c_prev,
    float* __restrict__ c_out,
    bf16* __restrict__ h_b16)
{
  constexpr int BM = MT * 32;
  __shared__ __align__(16) bf16 sA[BM * 64];
  __shared__ __align__(16) bf16 sB[128 * 64];
  const int tid = threadIdx.x;
  const int lane = tid & 63;
  const int quad = lane >> 4, cl = lane & 15;
  const int wave = tid >> 6;
  const int wr = wave >> 1, wc = wave & 1;
  const int bm0 = blockIdx.x * BM;
  const int j0 = blockIdx.y * 32;

  const bf16* ra[MT][2];
  const bf16* rb[4][2];
#pragma unroll
  for (int mi = 0; mi < MT; ++mi)
#pragma unroll
    for (int kh = 0; kh < 2; ++kh) {
      int row = wr * (MT * 16) + mi * 16 + cl;
      ra[mi][kh] = &sA[row * 64 + (((kh * 4 + quad) ^ (row & 7))) * 8];
    }
#pragma unroll
  for (int g = 0; g < 4; ++g)
#pragma unroll
    for (int kh = 0; kh < 2; ++kh) {
      int row = g * 32 + wc * 16 + cl;
      rb[g][kh] = &sB[row * 64 + (((kh * 4 + quad) ^ (row & 7))) * 8];
    }

  f32x4 acc[MT][4];
#pragma unroll
  for (int mi = 0; mi < MT; ++mi)
#pragma unroll
    for (int g = 0; g < 4; ++g) acc[mi][g] = f32x4{0.f, 0.f, 0.f, 0.f};

  const bf16* pa[MT];
  const bf16* pb[4];
#pragma unroll
  for (int ia = 0; ia < MT; ++ia) {
    int e = ia * 256 + tid, row = e >> 3, sl = e & 7;
    pa[ia] = A0 + (size_t)((bm0 + row) * a0s + a0off + (sl ^ (row & 7)) * 8);
  }
#pragma unroll
  for (int ib = 0; ib < 4; ++ib) {
    int e = ib * 256 + tid, row = e >> 3, sl = e & 7;
    int wrow = (row >> 5) * HIDDEN + j0 + (row & 31);
    pb[ib] = B0 + (size_t)(wrow * b0s + (sl ^ (row & 7)) * 8);
  }

  auto ktile = [&]() {
#pragma unroll
    for (int ia = 0; ia < MT; ++ia) {
      async16(pa[ia], sA + (ia * 256 + tid) * 8);
      pa[ia] += 64;
    }
#pragma unroll
    for (int ib = 0; ib < 4; ++ib) {
      async16(pb[ib], sB + (ib * 256 + tid) * 8);
      pb[ib] += 64;
    }
    __syncthreads();
#pragma unroll
    for (int kh = 0; kh < 2; ++kh) {
      bf16x8 af[MT], bfr[4];
#pragma unroll
      for (int mi = 0; mi < MT; ++mi) af[mi] = *(const bf16x8*)ra[mi][kh];
#pragma unroll
      for (int g = 0; g < 4; ++g) bfr[g] = *(const bf16x8*)rb[g][kh];
#pragma unroll
      for (int mi = 0; mi < MT; ++mi)
#pragma unroll
        for (int g = 0; g < 4; ++g)
          acc[mi][g] = __builtin_amdgcn_mfma_f32_16x16x32_bf16(af[mi], bfr[g], acc[mi][g], 0, 0, 0);
    }
    __syncthreads();
  };

  for (int kt = 0; kt < KT0; ++kt) ktile();
  if (KT1 > 0) {
#pragma unroll
    for (int ia = 0; ia < MT; ++ia) {
      int e = ia * 256 + tid, row = e >> 3, sl = e & 7;
      pa[ia] = A1 + (size_t)((bm0 + row) * a1s + (sl ^ (row & 7)) * 8);
    }
#pragma unroll
    for (int ib = 0; ib < 4; ++ib) {
      int e = ib * 256 + tid, row = e >> 3, sl = e & 7;
      int wrow = (row >> 5) * HIDDEN + j0 + (row & 31);
      pb[ib] = B1 + (size_t)(wrow * b1s + (sl ^ (row & 7)) * 8);
    }
    for (int kt = 0; kt < KT1; ++kt) ktile();
  }

  const int j = j0 + wc * 16 + cl;
  float bI = bias0[j] + bias1[j];
  float bF = bias0[HIDDEN + j] + bias1[HIDDEN + j];
  float bG = bias0[2 * HIDDEN + j] + bias1[2 * HIDDEN + j];
  float bO = bias0[3 * HIDDEN + j] + bias1[3 * HIDDEN + j];
#pragma unroll
  for (int mi = 0; mi < MT; ++mi) {
    int rb_ = bm0 + wr * (MT * 16) + mi * 16 + quad * 4;
#pragma unroll
    for (int r = 0; r < 4; ++r) {
      int row = rb_ + r;
      float iv = fast_sig(acc[mi][0][r] + bI);
      float fv = fast_sig(acc[mi][1][r] + bF);
      float gv = fast_tanh(acc[mi][2][r] + bG);
      float ov = fast_sig(acc[mi][3][r] + bO);
      float cp = c_prev ? c_prev[(size_t)row * HIDDEN + j] : 0.f;
      float cn = fv * cp + iv * gv;
      float hn = ov * fast_tanh(cn);
      c_out[(size_t)row * HIDDEN + j] = cn;
      h_b16[(size_t)row * HIDDEN + j] = (bf16)hn;
    }
  }
}

// ---------------- tree cell GEMM: BM=32, K=512, xp_add(bf16) + avg'd c -----
__global__ __launch_bounds__(256, 2) void cell_tree(
    const bf16* __restrict__ hA,
    const bf16* __restrict__ W,
    const float* __restrict__ bhh,
    const bf16* __restrict__ xp,
    const float* __restrict__ c_prev,
    float* __restrict__ c_out,
    bf16* __restrict__ h_out,
    float* __restrict__ h_f32)
{
  __shared__ __align__(16) bf16 sA[32 * 64];
  __shared__ __align__(16) bf16 sB[128 * 64];
  const int tid = threadIdx.x;
  const int lane = tid & 63;
  const int quad = lane >> 4, cl = lane & 15;
  const int wave = tid >> 6;
  const int wr = wave >> 1, wc = wave & 1;
  const int bm0 = blockIdx.x * 32;
  const int j0 = blockIdx.y * 32;

  const bf16* ra[2];
  const bf16* rb[4][2];
#pragma unroll
  for (int kh = 0; kh < 2; ++kh) {
    int row = wr * 16 + cl;
    ra[kh] = &sA[row * 64 + (((kh * 4 + quad) ^ (row & 7))) * 8];
  }
#pragma unroll
  for (int g = 0; g < 4; ++g)
#pragma unroll
    for (int kh = 0; kh < 2; ++kh) {
      int row = g * 32 + wc * 16 + cl;
      rb[g][kh] = &sB[row * 64 + (((kh * 4 + quad) ^ (row & 7))) * 8];
    }

  f32x4 acc[4];
#pragma unroll
  for (int g = 0; g < 4; ++g) acc[g] = f32x4{0.f, 0.f, 0.f, 0.f};

  int row_a = tid >> 3, sl_a = tid & 7;
  const bf16* pa = hA + (size_t)((bm0 + row_a) * HIDDEN + (sl_a ^ (row_a & 7)) * 8);
  const bf16* pb[4];
#pragma unroll
  for (int ib = 0; ib < 4; ++ib) {
    int e = ib * 256 + tid, row = e >> 3, sl = e & 7;
    int wrow = (row >> 5) * HIDDEN + j0 + (row & 31);
    pb[ib] = W + (size_t)(wrow * HIDDEN + (sl ^ (row & 7)) * 8);
  }

  for (int kt = 0; kt < 8; ++kt) {
    async16(pa, sA + tid * 8);
    pa += 64;
#pragma unroll
    for (int ib = 0; ib < 4; ++ib) {
      async16(pb[ib], sB + (ib * 256 + tid) * 8);
      pb[ib] += 64;
    }
    __syncthreads();
#pragma unroll
    for (int kh = 0; kh < 2; ++kh) {
      bf16x8 af = *(const bf16x8*)ra[kh];
#pragma unroll
      for (int g = 0; g < 4; ++g) {
        bf16x8 bfr = *(const bf16x8*)rb[g][kh];
        acc[g] = __builtin_amdgcn_mfma_f32_16x16x32_bf16(af, bfr, acc[g], 0, 0, 0);
      }
    }
    __syncthreads();
  }

  const int j = j0 + wc * 16 + cl;
  float bI = bhh[j], bF = bhh[HIDDEN + j];
  float bG = bhh[2 * HIDDEN + j], bO = bhh[3 * HIDDEN + j];
  int rb0 = bm0 + wr * 16 + quad * 4;
#pragma unroll
  for (int r = 0; r < 4; ++r) {
    int row = rb0 + r;
    const bf16* xr = xp + (size_t)row * 2048;
    float gi = acc[0][r] + bI + (float)xr[j];
    float gf = acc[1][r] + bF + (float)xr[HIDDEN + j];
    float gg = acc[2][r] + bG + (float)xr[2 * HIDDEN + j];
    float go = acc[3][r] + bO + (float)xr[3 * HIDDEN + j];
    float cp = c_prev[(size_t)row * HIDDEN + j];
    float cn = fast_sig(gf) * cp + fast_sig(gi) * fast_tanh(gg);
    float hn = fast_sig(go) * fast_tanh(cn);
    c_out[(size_t)row * HIDDEN + j] = cn;
    h_out[(size_t)row * HIDDEN + j] = (bf16)hn;
    if (h_f32) h_f32[(size_t)row * HIDDEN + j] = hn;
  }
}

// ---------------- plain GEMM (BK=32, swizzled): concat(A0,A1,A2)·B^T -------
template <int MT>
__global__ __launch_bounds__(256, 2) void plain_gemm(
    const bf16* __restrict__ A0, int a0s, int a0kt,
    const bf16* __restrict__ A1, int a1s, int a1kt,
    const bf16* __restrict__ A2, int a2s, int a2kt,
    const bf16* __restrict__ B, int bs,
    const float* __restrict__ bias, int do_relu,
    bf16* __restrict__ outh, int Ntot)
{
  constexpr int BM = MT * 32;
  __shared__ __align__(16) bf16 sA[BM * 32];
  __shared__ __align__(16) bf16 sB[128 * 32];
  const int tid = threadIdx.x;
  const int lane = tid & 63;
  const int quad = lane >> 4, cl = lane & 15;
  const int wave = tid >> 6;
  const int wr = wave >> 1, wc = wave & 1;
  const int bm0 = blockIdx.x * BM;
  const int bn0 = blockIdx.y * 128;

  f32x4 acc[MT][4];
#pragma unroll
  for (int mi = 0; mi < MT; ++mi)
#pragma unroll
    for (int ni = 0; ni < 4; ++ni) acc[mi][ni] = f32x4{0.f, 0.f, 0.f, 0.f};

  const int nkt = a0kt + a1kt + a2kt;
  for (int kt = 0; kt < nkt; ++kt) {
    const bf16* abase; int astr, acol;
    if (kt < a0kt)            { abase = A0; astr = a0s; acol = kt * 32; }
    else if (kt < a0kt + a1kt){ abase = A1; astr = a1s; acol = (kt - a0kt) * 32; }
    else                      { abase = A2; astr = a2s; acol = (kt - a0kt - a1kt) * 32; }
#pragma unroll
    for (int ia = 0; ia < MT / 2; ++ia) {
      int e = ia * 256 + tid;
      int row = e >> 2, sl = e & 3;
      int src = sl ^ ((row >> 1) & 3);
      async16(abase + (size_t)(bm0 + row) * astr + acol + src * 8, sA + e * 8);
    }
#pragma unroll
    for (int ib = 0; ib < 2; ++ib) {
      int e = ib * 256 + tid;
      int row = e >> 2, sl = e & 3;
      int src = sl ^ ((row >> 1) & 3);
      async16(B + (size_t)(bn0 + row) * bs + kt * 32 + src * 8, sB + e * 8);
    }
    __syncthreads();
    bf16x8 af[MT], bfr[4];
#pragma unroll
    for (int mi = 0; mi < MT; ++mi) {
      int row = wr * (MT * 16) + mi * 16 + cl;
      int sl = quad ^ ((row >> 1) & 3);
      af[mi] = *(const bf16x8*)&sA[row * 32 + sl * 8];
    }
#pragma unroll
    for (int ni = 0; ni < 4; ++ni) {
      int row = wc * 64 + ni * 16 + cl;
      int sl = quad ^ ((row >> 1) & 3);
      bfr[ni] = *(const bf16x8*)&sB[row * 32 + sl * 8];
    }
#pragma unroll
    for (int mi = 0; mi < MT; ++mi)
#pragma unroll
      for (int ni = 0; ni < 4; ++ni)
        acc[mi][ni] = __builtin_amdgcn_mfma_f32_16x16x32_bf16(af[mi], bfr[ni], acc[mi][ni], 0, 0, 0);
    __syncthreads();
  }

#pragma unroll
  for (int mi = 0; mi < MT; ++mi) {
    int rb = bm0 + wr * (MT * 16) + mi * 16 + quad * 4;
#pragma unroll
    for (int ni = 0; ni < 4; ++ni) {
      int col = bn0 + wc * 64 + ni * 16 + cl;
      float bv = bias ? bias[col] : 0.f;
#pragma unroll
      for (int r = 0; r < 4; ++r) {
        int row = rb + r;
        float v = acc[mi][ni][r] + bv;
        if (do_relu) v = fmaxf(v, 0.f);
        outh[(size_t)row * Ntot + col] = (bf16)v;
      }
    }
  }
}

// ---------------- tree gather: hA=bf16(0.5(h[m0]+h[m1])), c likewise -------
__global__ void gather_h(const int* __restrict__ map, const int* __restrict__ flags,
                         int level,
                         const bf16* __restrict__ h_src, const float* __restrict__ c_src,
                         bf16* __restrict__ hA, float* __restrict__ c_dst)
{
  int n = blockIdx.x, t = threadIdx.x;
  long base = (long)level * 2048 + n * 2;
  int m0, m1;
  if (flags[0]) { m0 = map[base * 2]; m1 = map[base * 2 + 2]; }
  else          { m0 = map[base];     m1 = map[base + 1]; }
  float h0 = m0 ? (float)h_src[(size_t)(m0 - 1) * HIDDEN + t] : 0.f;
  float h1 = m1 ? (float)h_src[(size_t)(m1 - 1) * HIDDEN + t] : 0.f;
  float c0 = m0 ? c_src[(size_t)(m0 - 1) * HIDDEN + t] : 0.f;
  float c1 = m1 ? c_src[(size_t)(m1 - 1) * HIDDEN + t] : 0.f;
  hA[(size_t)n * HIDDEN + t] = (bf16)(0.5f * (h0 + h1));
  c_dst[(size_t)n * HIDDEN + t] = 0.5f * (c0 + c1);
}

// level-15 cell: zero state -> gates = xp2[15] + bhh
__global__ void cell0(const bf16* __restrict__ xp,
                      const float* __restrict__ bhh,
                      bf16* __restrict__ h, float* __restrict__ c)
{
  int n = blockIdx.x, j = threadIdx.x;
  float g[4];
#pragma unroll
  for (int k = 0; k < 4; ++k)
    g[k] = (float)xp[(size_t)n * 2048 + k * 512 + j] + bhh[k * 512 + j];
  float cv = fast_sig(g[0]) * fast_tanh(g[2]);
  h[(size_t)n * HIDDEN + j] = (bf16)(fast_sig(g[3]) * fast_tanh(cv));
  c[(size_t)n * HIDDEN + j] = cv;
}

// ---------------- deterministic batchnorm ----------------
__global__ void bn_reduce_b16(const bf16* __restrict__ x, int rpb, int F,
                              float* __restrict__ partials) {
  int col = threadIdx.x, b = blockIdx.x;
  const bf16* p = x + (size_t)b * rpb * F + col;
  float s = 0.f, q = 0.f;
  for (int r = 0; r < rpb; ++r) { float v = (float)p[(size_t)r * F]; s += v; q += v * v; }
  partials[(size_t)b * 2 * F + col] = s;
  partials[(size_t)b * 2 * F + F + col] = q;
}

__global__ void bn_reduce_f32(const float* __restrict__ x, int rpb, int F,
                              float* __restrict__ partials) {
  int col = threadIdx.x, b = blockIdx.x;
  const float* p = x + (size_t)b * rpb * F + col;
  float s = 0.f, q = 0.f;
  for (int r = 0; r < rpb; ++r) { float v = p[(size_t)r * F]; s += v; q += v * v; }
  partials[(size_t)b * 2 * F + col] = s;
  partials[(size_t)b * 2 * F + F + col] = q;
}

__global__ void bn_final(const float* __restrict__ partials, int nb, int F,
                         const float* __restrict__ g, const float* __restrict__ b,
                         float invB, float* __restrict__ scale, float* __restrict__ shift) {
  int j = threadIdx.x;
  float s = 0.f, q = 0.f;
  for (int i = 0; i < nb; ++i) {
    s += partials[(size_t)i * 2 * F + j];
    q += partials[(size_t)i * 2 * F + F + j];
  }
  float mu = s * invB;
  float var = fmaxf(q * invB - mu * mu, 0.f);
  float sc = g[j] * rsqrtf(var + 1e-5f);
  scale[j] = sc;
  shift[j] = b[j] - sc * mu;
}

__global__ void bn_apply_mid(const bf16* __restrict__ x, const float* __restrict__ scale,
                             const float* __restrict__ shift, int Fmask, size_t total,
                             bf16* __restrict__ out) {
  for (size_t i = blockIdx.x * (size_t)blockDim.x + threadIdx.x; i < total;
       i += (size_t)gridDim.x * blockDim.x) {
    int j = (int)(i & (size_t)Fmask);
    out[i] = (bf16)(scale[j] * (float)x[i] + shift[j]);
  }
}

__global__ void bn_apply_out(const float* __restrict__ x, const float* __restrict__ scale,
                             const float* __restrict__ shift, int Fmask, size_t total,
                             float* __restrict__ out) {
  for (size_t i = blockIdx.x * (size_t)blockDim.x + threadIdx.x; i < total;
       i += (size_t)gridDim.x * blockDim.x) {
    int j = (int)(i & (size_t)Fmask);
    out[i] = scale[j] * x[i] + shift[j];
  }
}

// ---------------------------------------------------------------------------
extern "C" void kernel_launch(void* const* d_in, const int* in_sizes, int n_in,
                              void* d_out, int out_size, void* d_ws, size_t ws_size,
                              hipStream_t stream) {
  const float* operators = (const float*)d_in[0];
  const float* extras    = (const float*)d_in[1];
  const float* conds     = (const float*)d_in[2];
  const int*   mapping   = (const int*)d_in[4];
  const float* b1ih = (const float*)d_in[7];
  const float* b1hh = (const float*)d_in[8];
  const float* condb = (const float*)d_in[10];
  const float* bn1g = (const float*)d_in[11];
  const float* bn1b = (const float*)d_in[12];
  const float* b2ih = (const float*)d_in[15];
  const float* b2hh = (const float*)d_in[16];
  const float* bn2g = (const float*)d_in[17];
  const float* bn2b = (const float*)d_in[18];

  char* ws = (char*)d_ws;
  size_t o = 0;
  auto alloc = [&](size_t bytes) {
    char* p = ws + o;
    o += (bytes + 255) & ~(size_t)255;
    return p;
  };
  bf16* conds_b = (bf16*)alloc((size_t)33554432 * 2);
  bf16* ops_b   = (bf16*)alloc((size_t)524288 * 2);
  bf16* ext_b   = (bf16*)alloc((size_t)524288 * 2);
  bf16* w1ih_b  = (bf16*)alloc((size_t)524288 * 2);
  bf16* w1hh_b  = (bf16*)alloc((size_t)1048576 * 2);
  bf16* condw_b = (bf16*)alloc((size_t)131072 * 2);
  bf16* w2ih_b  = (bf16*)alloc((size_t)655360 * 2);
  bf16* w2hh_b  = (bf16*)alloc((size_t)1048576 * 2);
  bf16* h1[2];
  h1[0] = (bf16*)alloc((size_t)16384 * 512 * 2);
  h1[1] = (bf16*)alloc((size_t)16384 * 512 * 2);
  float* c1 = (float*)alloc((size_t)16384 * 512 * 4);
  bf16* last_relu = (bf16*)alloc((size_t)16384 * 256 * 2);
  bf16* last_bn = (bf16*)alloc((size_t)16384 * 256 * 2);
  bf16* h2 = (bf16*)alloc((size_t)1024 * 512 * 2);
  bf16* hA = (bf16*)alloc((size_t)1024 * 512 * 2);
  float* c2a = (float*)alloc((size_t)1024 * 512 * 4);
  float* c2b = (float*)alloc((size_t)1024 * 512 * 4);
  float* h2f = (float*)alloc((size_t)1024 * 512 * 4);
  float* partials = (float*)alloc((size_t)64 * 1024 * 4);
  float* scale1 = (float*)alloc(256 * 4);
  float* shift1 = (float*)alloc(256 * 4);
  float* scale2 = (float*)alloc(512 * 4);
  float* shift2 = (float*)alloc(512 * 4);
  int* flags = (int*)alloc(256);
  bf16* xp2 = (bf16*)alloc((size_t)16384 * 2048 * 2);

  prep<<<18561, 256, 0, stream>>>(
      conds, conds_b,
      operators, ops_b, extras, ext_b,
      (const float*)d_in[5], w1ih_b, (const float*)d_in[6], w1hh_b,
      (const float*)d_in[9], condw_b, (const float*)d_in[13], w2ih_b,
      (const float*)d_in[14], w2hh_b,
      mapping, flags);

  // -------- LSTM1: 8 fused K=768 GEMM+cell steps (BM=128 x BN=128) --------
  cell_gemm<4, 4, 0><<<dim3(128, 16), 256, 0, stream>>>(
      conds_b, 0, 2048, nullptr, 512,
      w1ih_b, 256, w1hh_b, 512,
      b1ih, b1hh, nullptr, c1, h1[1]);
  for (int t = 1; t < 8; ++t) {
    cell_gemm<4, 4, 8><<<dim3(128, 16), 256, 0, stream>>>(
        conds_b, t * 256, 2048, h1[t & 1], 512,
        w1ih_b, 256, w1hh_b, 512,
        b1ih, b1hh, c1, c1, h1[(t + 1) & 1]);
  }

  // -------- last = relu(h1 @ condW^T + condb); BN1 --------
  plain_gemm<2><<<dim3(256, 2), 256, 0, stream>>>(
      h1[0], 512, 16, nullptr, 0, 0, nullptr, 0, 0,
      condw_b, 512, condb, 1, last_relu, 256);
  bn_reduce_b16<<<64, 256, 0, stream>>>(last_relu, 256, 256, partials);
  bn_final<<<1, 256, 0, stream>>>(partials, 64, 256, bn1g, bn1b, 1.f / 16384.f, scale1, shift1);
  bn_apply_mid<<<1024, 256, 0, stream>>>(last_relu, scale1, shift1, 255,
                                         (size_t)16384 * 256, last_bn);

  // -------- xp2 = concat(ops, extras, last_bn) @ W2ih^T + b2ih (bf16) -----
  plain_gemm<4><<<dim3(128, 16), 256, 0, stream>>>(
      ops_b, 32, 1, ext_b, 32, 1, last_bn, 256, 8,
      w2ih_b, 320, b2ih, 0, xp2, 2048);

  // -------- LSTM2 tree: gather (1024 blk) + BM=32 GEMM (512 blk) ----------
  size_t lvl_sz = (size_t)1024 * 2048;
  cell0<<<1024, 512, 0, stream>>>(xp2 + 15 * lvl_sz, b2hh, h2, c2a);
  for (int idx = 14; idx >= 0; --idx) {
    gather_h<<<1024, 512, 0, stream>>>(mapping, flags, idx, h2, c2a, hA, c2b);
    cell_tree<<<dim3(32, 16), 256, 0, stream>>>(
        hA, w2hh_b, b2hh, xp2 + idx * lvl_sz, c2b, c2a, h2,
        (idx == 0) ? h2f : nullptr);
  }

  // -------- BN2 -> output --------
  bn_reduce_f32<<<16, 512, 0, stream>>>(h2f, 64, 512, partials);
  bn_final<<<1, 512, 0, stream>>>(partials, 16, 512, bn2g, bn2b, 1.f / 1024.f, scale2, shift2);
  bn_apply_out<<<512, 256, 0, stream>>>(h2f, scale2, shift2, 511,
                                        (size_t)1024 * 512, (float*)d_out);
}